// Round 1
// baseline (1015.422 us; speedup 1.0000x reference)
//
#include <hip/hip_runtime.h>
#include <math.h>

#define LEN 17821
#define DMODEL 384
#define NHEAD 8
#define DHEAD 48

// ---------------------------------------------------------------------------
// Elementwise add: q = src + pos (float4 vectorized)
// ---------------------------------------------------------------------------
__global__ __launch_bounds__(256)
void add_kernel(const float* __restrict__ a, const float* __restrict__ b,
                float* __restrict__ o, int n4) {
    int i = blockIdx.x * 256 + threadIdx.x;
    if (i < n4) {
        float4 x = ((const float4*)a)[i];
        float4 y = ((const float4*)b)[i];
        float4 r = make_float4(x.x + y.x, x.y + y.y, x.z + y.z, x.w + y.w);
        ((float4*)o)[i] = r;
    }
}

// ---------------------------------------------------------------------------
// Generic fp32 GEMM: C[M,N] = A[M,K] @ W[N,K]^T + bias (+relu) (+residual)
// Tiles 64x64x16, 256 threads, 4x4 microtile per thread.
// N must be a multiple of 64, K a multiple of 16.
// ---------------------------------------------------------------------------
template<bool RELU, bool HAS_RES>
__global__ __launch_bounds__(256)
void gemm_kernel(const float* __restrict__ A, int lda,
                 const float* __restrict__ W,            // [N,K] row-major
                 const float* __restrict__ bias,         // [N]
                 const float* __restrict__ Res, int ldres,
                 float* __restrict__ C, int ldc,
                 int M, int N, int K) {
    __shared__ float As[16][64];
    __shared__ float Ws[16][64];
    int tid = threadIdx.x;
    int lm = tid >> 2;            // 0..63
    int lk = (tid & 3) << 2;      // 0,4,8,12
    int bx = blockIdx.x, by = blockIdx.y;
    int arow = by * 64 + lm;
    int wrow = bx * 64 + lm;      // always < N (N % 64 == 0)
    int tx = tid & 15, ty = tid >> 4;
    float acc[4][4] = {};
    for (int k0 = 0; k0 < K; k0 += 16) {
        float4 av = make_float4(0.f, 0.f, 0.f, 0.f);
        if (arow < M) av = *(const float4*)(A + (size_t)arow * lda + k0 + lk);
        float4 wv = *(const float4*)(W + (size_t)wrow * K + k0 + lk);
        __syncthreads();
        As[lk + 0][lm] = av.x; As[lk + 1][lm] = av.y;
        As[lk + 2][lm] = av.z; As[lk + 3][lm] = av.w;
        Ws[lk + 0][lm] = wv.x; Ws[lk + 1][lm] = wv.y;
        Ws[lk + 2][lm] = wv.z; Ws[lk + 3][lm] = wv.w;
        __syncthreads();
        #pragma unroll
        for (int k = 0; k < 16; ++k) {
            float4 a4 = *(const float4*)(&As[k][ty * 4]);
            float4 b4 = *(const float4*)(&Ws[k][tx * 4]);
            float aa[4] = {a4.x, a4.y, a4.z, a4.w};
            float bb[4] = {b4.x, b4.y, b4.z, b4.w};
            #pragma unroll
            for (int i = 0; i < 4; ++i)
                #pragma unroll
                for (int j = 0; j < 4; ++j)
                    acc[i][j] += aa[i] * bb[j];
        }
    }
    int cn = bx * 64 + tx * 4;
    float4 bv = *(const float4*)(bias + cn);
    float bb[4] = {bv.x, bv.y, bv.z, bv.w};
    #pragma unroll
    for (int i = 0; i < 4; ++i) {
        int cm = by * 64 + ty * 4 + i;
        if (cm >= M) continue;
        float r[4];
        #pragma unroll
        for (int j = 0; j < 4; ++j) {
            float v = acc[i][j] + bb[j];
            if (RELU) v = fmaxf(v, 0.f);
            r[j] = v;
        }
        if (HAS_RES) {
            float4 rv = *(const float4*)(Res + (size_t)cm * ldres + cn);
            r[0] += rv.x; r[1] += rv.y; r[2] += rv.z; r[3] += rv.w;
        }
        *(float4*)(C + (size_t)cm * ldc + cn) = make_float4(r[0], r[1], r[2], r[3]);
    }
}

// ---------------------------------------------------------------------------
// MSDA core: one wave per (token, head). Softmax over 16 logits in-wave,
// then 4 levels x 4 points bilinear gather-accumulate over 48 dims.
// offattn layout: row t = [off(256) | attn_logits(128)], stride 384.
// ---------------------------------------------------------------------------
__global__ __launch_bounds__(256)
void msda_kernel(const float* __restrict__ value,     // [LEN,384] (H*DH cols)
                 const float* __restrict__ offattn,   // [LEN,384]
                 const float* __restrict__ refpts,    // [LEN,4,2]
                 float* __restrict__ out) {           // [LEN,384]
    const int HLs[4] = {100, 50, 25, 13};
    const int WLs[4] = {134, 67, 34, 17};
    const int STs[4] = {0, 13400, 16750, 17600};
    int gw = (blockIdx.x * 256 + threadIdx.x) >> 6;
    int lane = threadIdx.x & 63;
    if (gw >= LEN * NHEAD) return;
    int t = gw >> 3, h = gw & 7;

    const float* lgp = offattn + (size_t)t * 384 + 256 + h * 16;
    float w[16];
    float mx = -3.4e38f;
    #pragma unroll
    for (int s = 0; s < 16; ++s) { w[s] = lgp[s]; mx = fmaxf(mx, w[s]); }
    float sum = 0.f;
    #pragma unroll
    for (int s = 0; s < 16; ++s) { w[s] = __expf(w[s] - mx); sum += w[s]; }
    float inv = 1.0f / sum;

    int d = lane;
    bool active = d < DHEAD;
    const float* offp = offattn + (size_t)t * 384 + h * 32;
    const float* rp = refpts + (size_t)t * 8;
    const float* vh = value + h * DHEAD + (active ? d : 0);
    float acc = 0.f;

    #pragma unroll
    for (int lvl = 0; lvl < 4; ++lvl) {
        float Wl = (float)WLs[lvl], Hl = (float)HLs[lvl];
        int Wli = WLs[lvl], Hli = HLs[lvl], st = STs[lvl];
        float rx = rp[lvl * 2 + 0], ry = rp[lvl * 2 + 1];
        #pragma unroll
        for (int p = 0; p < 4; ++p) {
            float ox = offp[lvl * 8 + p * 2 + 0];
            float oy = offp[lvl * 8 + p * 2 + 1];
            float locx = rx + ox / Wl;
            float locy = ry + oy / Hl;
            float x = locx * Wl - 0.5f;
            float y = locy * Hl - 0.5f;
            float x0f = floorf(x), y0f = floorf(y);
            float dx = x - x0f, dy = y - y0f;
            int x0 = (int)x0f, y0 = (int)y0f;
            float aw = w[lvl * 4 + p] * inv;
            #pragma unroll
            for (int c = 0; c < 4; ++c) {
                int ox2 = c & 1, oy2 = c >> 1;
                int xi = x0 + ox2, yi = y0 + oy2;
                if (xi >= 0 && xi < Wli && yi >= 0 && yi < Hli) {  // wave-uniform
                    float cw = (ox2 ? dx : 1.f - dx) * (oy2 ? dy : 1.f - dy);
                    float g = value[(size_t)(st + yi * Wli + xi) * 384 + h * DHEAD + d % DHEAD];
                    if (!active) g = 0.f;
                    acc += aw * cw * g;
                }
            }
        }
    }
    if (active) out[(size_t)t * 384 + h * DHEAD + d] = acc;
    (void)vh;
}

// ---------------------------------------------------------------------------
// Split LayerNorm over [0:256] (xy) and [256:384] (zd).
// grid (LEN, 2); block 256. Optional residual R (added to X before LN).
// ---------------------------------------------------------------------------
__global__ __launch_bounds__(256)
void ln_kernel(const float* __restrict__ X, const float* __restrict__ R,
               const float* __restrict__ gxy, const float* __restrict__ bxy,
               const float* __restrict__ gzd, const float* __restrict__ bzd,
               float* __restrict__ out) {
    __shared__ float s1[256], s2[256];
    int t = blockIdx.x;
    int seg = blockIdx.y;
    int n = seg ? 128 : 256;
    int off = seg ? 256 : 0;
    const float* g = seg ? gzd : gxy;
    const float* b = seg ? bzd : bxy;
    int i = threadIdx.x;
    float x = 0.f;
    if (i < n) {
        x = X[(size_t)t * 384 + off + i];
        if (R) x += R[(size_t)t * 384 + off + i];
    }
    s1[i] = x; s2[i] = x * x;
    __syncthreads();
    for (int st = 128; st > 0; st >>= 1) {
        if (i < st) { s1[i] += s1[i + st]; s2[i] += s2[i + st]; }
        __syncthreads();
    }
    float m = s1[0] / n;
    float v = s2[0] / n - m * m;
    float iv = rsqrtf(v + 1e-5f);
    if (i < n) out[(size_t)t * 384 + off + i] = (x - m) * iv * g[i] + b[i];
}

// ---------------------------------------------------------------------------
extern "C" void kernel_launch(void* const* d_in, const int* in_sizes, int n_in,
                              void* d_out, int out_size, void* d_ws, size_t ws_size,
                              hipStream_t stream) {
    const float* src    = (const float*)d_in[0];
    const float* pos    = (const float*)d_in[3];
    const float* refpts = (const float*)d_in[4];
    const float* W_off  = (const float*)d_in[8];
    const float* b_off  = (const float*)d_in[9];
    const float* W_attn = (const float*)d_in[10];
    const float* b_attn = (const float*)d_in[11];
    const float* W_val  = (const float*)d_in[12];
    const float* b_val  = (const float*)d_in[13];
    const float* W_out  = (const float*)d_in[14];
    const float* b_out  = (const float*)d_in[15];
    const float* g1xy = (const float*)d_in[16]; const float* b1xy = (const float*)d_in[17];
    const float* g1zd = (const float*)d_in[18]; const float* b1zd = (const float*)d_in[19];
    const float* fxy_w1 = (const float*)d_in[20]; const float* fxy_b1 = (const float*)d_in[21];
    const float* fxy_w2 = (const float*)d_in[22]; const float* fxy_b2 = (const float*)d_in[23];
    const float* fxy_g  = (const float*)d_in[24]; const float* fxy_b  = (const float*)d_in[25];
    const float* fzd_w1 = (const float*)d_in[26]; const float* fzd_b1 = (const float*)d_in[27];
    const float* fzd_w2 = (const float*)d_in[28]; const float* fzd_b2 = (const float*)d_in[29];
    const float* fzd_g  = (const float*)d_in[30]; const float* fzd_b  = (const float*)d_in[31];

    float* out = (float*)d_out;
    float* ws = (float*)d_ws;
    size_t Rn = (size_t)LEN * DMODEL;
    float* Aq = ws;            // q, later h1 (post-LN1)
    float* Bv = ws + Rn;       // value, later ffn2 output
    float* Cc = ws + 2 * Rn;   // off(256) | attn logits(128)
    float* Dd = ws + 3 * Rn;   // msda out, later relu intermediates
    float* Ee = out;           // src2 (out-proj) scratch; final LN2 overwrites

    dim3 blk(256);
    int mgrid = (LEN + 63) / 64;

    // q = src + pos
    int n4 = LEN * DMODEL / 4;
    add_kernel<<<(n4 + 255) / 256, 256, 0, stream>>>(src, pos, Aq, n4);

    // value = src @ W_val^T + b_val
    gemm_kernel<false, false><<<dim3(384 / 64, mgrid), blk, 0, stream>>>(
        src, 384, W_val, b_val, nullptr, 0, Bv, 384, LEN, 384, 384);
    // off = q @ W_off^T + b_off   (cols 0..255 of Cc)
    gemm_kernel<false, false><<<dim3(256 / 64, mgrid), blk, 0, stream>>>(
        Aq, 384, W_off, b_off, nullptr, 0, Cc, 384, LEN, 256, 384);
    // attn logits = q @ W_attn^T + b_attn   (cols 256..383 of Cc)
    gemm_kernel<false, false><<<dim3(128 / 64, mgrid), blk, 0, stream>>>(
        Aq, 384, W_attn, b_attn, nullptr, 0, Cc + 256, 384, LEN, 128, 384);

    // MSDA sampling -> Dd
    int nthreads = LEN * NHEAD * 64;
    msda_kernel<<<(nthreads + 255) / 256, 256, 0, stream>>>(Bv, Cc, refpts, Dd);

    // src2 = msda @ W_out^T + b_out -> Ee (d_out scratch)
    gemm_kernel<false, false><<<dim3(384 / 64, mgrid), blk, 0, stream>>>(
        Dd, 384, W_out, b_out, nullptr, 0, Ee, 384, LEN, 384, 384);

    // h1 = LN1(src + src2) -> Aq
    ln_kernel<<<dim3(LEN, 2), 256, 0, stream>>>(src, Ee, g1xy, b1xy, g1zd, b1zd, Aq);

    // FFN first GEMMs (relu) -> Dd
    gemm_kernel<true, false><<<dim3(256 / 64, mgrid), blk, 0, stream>>>(
        Aq, 384, fxy_w1, fxy_b1, nullptr, 0, Dd, 384, LEN, 256, 256);
    gemm_kernel<true, false><<<dim3(128 / 64, mgrid), blk, 0, stream>>>(
        Aq + 256, 384, fzd_w1, fzd_b1, nullptr, 0, Dd + 256, 384, LEN, 128, 128);

    // FFN second GEMMs + residual(h1) -> Bv
    gemm_kernel<false, true><<<dim3(256 / 64, mgrid), blk, 0, stream>>>(
        Dd, 384, fxy_w2, fxy_b2, Aq, 384, Bv, 384, LEN, 256, 256);
    gemm_kernel<false, true><<<dim3(128 / 64, mgrid), blk, 0, stream>>>(
        Dd + 256, 384, fzd_w2, fzd_b2, Aq + 256, 384, Bv + 256, 384, LEN, 128, 128);

    // LN2 -> d_out
    ln_kernel<<<dim3(LEN, 2), 256, 0, stream>>>(Bv, nullptr, fxy_g, fxy_b, fzd_g, fzd_b, out);
}

// Round 2
// 503.626 us; speedup vs baseline: 2.0162x; 2.0162x over previous
//
#include <hip/hip_runtime.h>
#include <math.h>

#define LEN 17821
#define DMODEL 384
#define NHEAD 8
#define DHEAD 48

typedef float floatx4 __attribute__((ext_vector_type(4)));
typedef short shortx8 __attribute__((ext_vector_type(8)));

__device__ inline unsigned short f2bf(float f) {
    unsigned int u = __float_as_uint(f);
    u += 0x7FFFu + ((u >> 16) & 1u);
    return (unsigned short)(u >> 16);
}

// ---------------------------------------------------------------------------
// Elementwise add: q = src + pos (float4 vectorized)
// ---------------------------------------------------------------------------
__global__ __launch_bounds__(256)
void add_kernel(const float* __restrict__ a, const float* __restrict__ b,
                float* __restrict__ o, int n4) {
    int i = blockIdx.x * 256 + threadIdx.x;
    if (i < n4) {
        float4 x = ((const float4*)a)[i];
        float4 y = ((const float4*)b)[i];
        ((float4*)o)[i] = make_float4(x.x + y.x, x.y + y.y, x.z + y.z, x.w + y.w);
    }
}

// ---------------------------------------------------------------------------
// bf16 MFMA GEMM: C[M,N] = A[M,K] @ W[N,K]^T + bias (+relu) (+residual)
// A,W fp32 in global, converted to bf16 while staging to LDS.
// 128x128 tile, BK=32, 256 threads = 4 waves in 2x2, each wave 64x64 via
// 4x4 tiles of mfma_f32_16x16x32_bf16. N % 128 == 0, K % 32 == 0.
// LDS row stride 40 ushorts (80B) to break bank-conflict power-of-2 stride.
// Fragment layouts (verified, guide §3): A[m=lane&15][k=(lane>>4)*8+j],
// B same addressing on W rows; C/D col=lane&15, row=(lane>>4)*4+reg.
// ---------------------------------------------------------------------------
#define TS 128
#define BK 32
#define LSTRIDE 40

template<bool RELU, bool HAS_RES>
__global__ __launch_bounds__(256)
void gemm_mfma(const float* __restrict__ A, int lda,
               const float* __restrict__ W,          // [N,K] row-major
               const float* __restrict__ bias,       // [N]
               const float* __restrict__ Res, int ldres,
               float* __restrict__ C, int ldc,
               int M, int N, int K) {
    __shared__ unsigned short As[TS * LSTRIDE];
    __shared__ unsigned short Ws[TS * LSTRIDE];
    int tid = threadIdx.x;
    int lane = tid & 63, wave = tid >> 6;
    int wr = (wave >> 1) * 64, wc = (wave & 1) * 64;
    int l15 = lane & 15, quad = lane >> 4;
    int srow = tid >> 1, shalf = tid & 1;
    int by = blockIdx.y, bx = blockIdx.x;
    int garow = by * TS + srow;
    const float* ap = A + (size_t)garow * lda + shalf * 16;
    const float* wp = W + (size_t)(bx * TS + srow) * K + shalf * 16;
    bool avalid = garow < M;
    unsigned short* as_dst = &As[srow * LSTRIDE + shalf * 16];
    unsigned short* ws_dst = &Ws[srow * LSTRIDE + shalf * 16];

    floatx4 acc[4][4];
    #pragma unroll
    for (int i = 0; i < 4; ++i)
        #pragma unroll
        for (int j = 0; j < 4; ++j)
            acc[i][j] = (floatx4){0.f, 0.f, 0.f, 0.f};

    for (int k0 = 0; k0 < K; k0 += BK) {
        float4 a0 = make_float4(0, 0, 0, 0), a1 = a0, a2 = a0, a3 = a0;
        if (avalid) {
            a0 = *(const float4*)(ap + k0 + 0);
            a1 = *(const float4*)(ap + k0 + 4);
            a2 = *(const float4*)(ap + k0 + 8);
            a3 = *(const float4*)(ap + k0 + 12);
        }
        float4 w0 = *(const float4*)(wp + k0 + 0);
        float4 w1 = *(const float4*)(wp + k0 + 4);
        float4 w2 = *(const float4*)(wp + k0 + 8);
        float4 w3 = *(const float4*)(wp + k0 + 12);
        __syncthreads();
        {
            shortx8 v0, v1;
            v0[0] = f2bf(a0.x); v0[1] = f2bf(a0.y); v0[2] = f2bf(a0.z); v0[3] = f2bf(a0.w);
            v0[4] = f2bf(a1.x); v0[5] = f2bf(a1.y); v0[6] = f2bf(a1.z); v0[7] = f2bf(a1.w);
            v1[0] = f2bf(a2.x); v1[1] = f2bf(a2.y); v1[2] = f2bf(a2.z); v1[3] = f2bf(a2.w);
            v1[4] = f2bf(a3.x); v1[5] = f2bf(a3.y); v1[6] = f2bf(a3.z); v1[7] = f2bf(a3.w);
            *(shortx8*)(as_dst + 0) = v0;
            *(shortx8*)(as_dst + 8) = v1;
            shortx8 u0, u1;
            u0[0] = f2bf(w0.x); u0[1] = f2bf(w0.y); u0[2] = f2bf(w0.z); u0[3] = f2bf(w0.w);
            u0[4] = f2bf(w1.x); u0[5] = f2bf(w1.y); u0[6] = f2bf(w1.z); u0[7] = f2bf(w1.w);
            u1[0] = f2bf(w2.x); u1[1] = f2bf(w2.y); u1[2] = f2bf(w2.z); u1[3] = f2bf(w2.w);
            u1[4] = f2bf(w3.x); u1[5] = f2bf(w3.y); u1[6] = f2bf(w3.z); u1[7] = f2bf(w3.w);
            *(shortx8*)(ws_dst + 0) = u0;
            *(shortx8*)(ws_dst + 8) = u1;
        }
        __syncthreads();
        shortx8 af[4], bf[4];
        #pragma unroll
        for (int i = 0; i < 4; ++i)
            af[i] = *(shortx8*)&As[(wr + i * 16 + l15) * LSTRIDE + quad * 8];
        #pragma unroll
        for (int j = 0; j < 4; ++j)
            bf[j] = *(shortx8*)&Ws[(wc + j * 16 + l15) * LSTRIDE + quad * 8];
        #pragma unroll
        for (int i = 0; i < 4; ++i)
            #pragma unroll
            for (int j = 0; j < 4; ++j)
                acc[i][j] = __builtin_amdgcn_mfma_f32_16x16x32_bf16(
                    af[i], bf[j], acc[i][j], 0, 0, 0);
    }

    #pragma unroll
    for (int j = 0; j < 4; ++j) {
        int col = bx * TS + wc + j * 16 + l15;
        float bv = bias[col];
        #pragma unroll
        for (int i = 0; i < 4; ++i) {
            #pragma unroll
            for (int r = 0; r < 4; ++r) {
                int row = by * TS + wr + i * 16 + quad * 4 + r;
                if (row < M) {
                    float v = acc[i][j][r] + bv;
                    if (RELU) v = fmaxf(v, 0.f);
                    if (HAS_RES) v += Res[(size_t)row * ldres + col];
                    C[(size_t)row * ldc + col] = v;
                }
            }
        }
    }
}

// ---------------------------------------------------------------------------
// MSDA v2: block = 4 tokens x 96 threads (8 heads x 12 float4 chunks).
// Phase 1: 32 threads do per-(tok,head) softmax -> aw[16] in LDS;
//          all threads compute per-point x0,y0,dx,dy in LDS.
// Phase 2: each thread gathers 16 points x 4 corners of float4, weights
//          predicated (clamped address always valid).
// ---------------------------------------------------------------------------
#define MTOK 4
__global__ __launch_bounds__(384)
void msda_v2(const float* __restrict__ value,    // [LEN,384]
             const float* __restrict__ offattn,  // [LEN,384]: off(256)|logits(128)
             const float* __restrict__ refpts,   // [LEN,4,2]
             float* __restrict__ out) {          // [LEN,384]
    __shared__ int   sx0[MTOK * 128], sy0[MTOK * 128];
    __shared__ float sdx[MTOK * 128], sdy[MTOK * 128], saw[MTOK * 128];
    constexpr int   Wi[4]  = {134, 67, 34, 17};
    constexpr int   Hi[4]  = {100, 50, 25, 13};
    constexpr int   STi[4] = {0, 13400, 16750, 17600};
    int t0 = blockIdx.x * MTOK;
    int tid = threadIdx.x;

    if (tid < 32) {
        int ti = tid >> 3, h = tid & 7, t = t0 + ti;
        if (t < LEN) {
            const float* lg = offattn + (size_t)t * 384 + 256 + h * 16;
            float w[16], mx = -3.4e38f;
            #pragma unroll
            for (int s = 0; s < 16; ++s) { w[s] = lg[s]; mx = fmaxf(mx, w[s]); }
            float sum = 0.f;
            #pragma unroll
            for (int s = 0; s < 16; ++s) { w[s] = __expf(w[s] - mx); sum += w[s]; }
            float inv = 1.0f / sum;
            #pragma unroll
            for (int s = 0; s < 16; ++s) saw[ti * 128 + h * 16 + s] = w[s] * inv;
        }
    }
    #pragma unroll
    for (int idx = tid; idx < MTOK * 128; idx += 384) {
        int ti = idx >> 7, rem = idx & 127, h = rem >> 4, p = rem & 15;
        int lvl = p >> 2, pp = p & 3;
        int t = t0 + ti;
        if (t < LEN) {
            float Wl = lvl == 0 ? 134.f : lvl == 1 ? 67.f : lvl == 2 ? 34.f : 17.f;
            float Hl = lvl == 0 ? 100.f : lvl == 1 ? 50.f : lvl == 2 ? 25.f : 13.f;
            const float* op = offattn + (size_t)t * 384 + h * 32 + lvl * 8 + pp * 2;
            float ox = op[0], oy = op[1];
            float rx = refpts[(size_t)t * 8 + lvl * 2];
            float ry = refpts[(size_t)t * 8 + lvl * 2 + 1];
            // loc*W - 0.5 = rx*W + ox - 0.5 (offsets divided by W then re-scaled)
            float x = rx * Wl + ox - 0.5f;
            float y = ry * Hl + oy - 0.5f;
            float x0 = floorf(x), y0 = floorf(y);
            sx0[idx] = (int)x0; sy0[idx] = (int)y0;
            sdx[idx] = x - x0;  sdy[idx] = y - y0;
        }
    }
    __syncthreads();

    int ti = tid / 96;
    int r = tid - ti * 96;
    int h = r / 12;
    int c = r - h * 12;
    int t = t0 + ti;
    if (t >= LEN) return;
    const float* vb = value + h * DHEAD + c * 4;
    float ax = 0.f, ay = 0.f, az = 0.f, aw4 = 0.f;
    #pragma unroll
    for (int p = 0; p < 16; ++p) {
        const int lvl = p >> 2;
        const int Wl = Wi[lvl], Hl = Hi[lvl], st = STi[lvl];
        int base = ti * 128 + h * 16 + p;
        int x0 = sx0[base], y0 = sy0[base];
        float dx = sdx[base], dy = sdy[base], aw = saw[base];
        float cw[4];
        cw[0] = (1.f - dx) * (1.f - dy);
        cw[1] = dx * (1.f - dy);
        cw[2] = (1.f - dx) * dy;
        cw[3] = dx * dy;
        #pragma unroll
        for (int c2 = 0; c2 < 4; ++c2) {
            int xi = x0 + (c2 & 1), yi = y0 + (c2 >> 1);
            bool valid = (xi >= 0) & (xi < Wl) & (yi >= 0) & (yi < Hl);
            int xc = min(max(xi, 0), Wl - 1);
            int yc = min(max(yi, 0), Hl - 1);
            float s = valid ? aw * cw[c2] : 0.f;
            const float4 g = *(const float4*)(vb + (size_t)(st + yc * Wl + xc) * 384);
            ax += s * g.x; ay += s * g.y; az += s * g.z; aw4 += s * g.w;
        }
    }
    *(float4*)(out + (size_t)t * 384 + h * DHEAD + c * 4) = make_float4(ax, ay, az, aw4);
}

// ---------------------------------------------------------------------------
// Split LayerNorm over [0:256] (xy) and [256:384] (zd).
// ---------------------------------------------------------------------------
__global__ __launch_bounds__(256)
void ln_kernel(const float* __restrict__ X, const float* __restrict__ R,
               const float* __restrict__ gxy, const float* __restrict__ bxy,
               const float* __restrict__ gzd, const float* __restrict__ bzd,
               float* __restrict__ out) {
    __shared__ float s1[256], s2[256];
    int t = blockIdx.x;
    int seg = blockIdx.y;
    int n = seg ? 128 : 256;
    int off = seg ? 256 : 0;
    const float* g = seg ? gzd : gxy;
    const float* b = seg ? bzd : bxy;
    int i = threadIdx.x;
    float x = 0.f;
    if (i < n) {
        x = X[(size_t)t * 384 + off + i];
        if (R) x += R[(size_t)t * 384 + off + i];
    }
    s1[i] = x; s2[i] = x * x;
    __syncthreads();
    for (int st = 128; st > 0; st >>= 1) {
        if (i < st) { s1[i] += s1[i + st]; s2[i] += s2[i + st]; }
        __syncthreads();
    }
    float m = s1[0] / n;
    float v = s2[0] / n - m * m;
    float iv = rsqrtf(v + 1e-5f);
    if (i < n) out[(size_t)t * 384 + off + i] = (x - m) * iv * g[i] + b[i];
}

// ---------------------------------------------------------------------------
extern "C" void kernel_launch(void* const* d_in, const int* in_sizes, int n_in,
                              void* d_out, int out_size, void* d_ws, size_t ws_size,
                              hipStream_t stream) {
    const float* src    = (const float*)d_in[0];
    const float* pos    = (const float*)d_in[3];
    const float* refpts = (const float*)d_in[4];
    const float* W_off  = (const float*)d_in[8];
    const float* b_off  = (const float*)d_in[9];
    const float* W_attn = (const float*)d_in[10];
    const float* b_attn = (const float*)d_in[11];
    const float* W_val  = (const float*)d_in[12];
    const float* b_val  = (const float*)d_in[13];
    const float* W_out  = (const float*)d_in[14];
    const float* b_out  = (const float*)d_in[15];
    const float* g1xy = (const float*)d_in[16]; const float* b1xy = (const float*)d_in[17];
    const float* g1zd = (const float*)d_in[18]; const float* b1zd = (const float*)d_in[19];
    const float* fxy_w1 = (const float*)d_in[20]; const float* fxy_b1 = (const float*)d_in[21];
    const float* fxy_w2 = (const float*)d_in[22]; const float* fxy_b2 = (const float*)d_in[23];
    const float* fxy_g  = (const float*)d_in[24]; const float* fxy_b  = (const float*)d_in[25];
    const float* fzd_w1 = (const float*)d_in[26]; const float* fzd_b1 = (const float*)d_in[27];
    const float* fzd_w2 = (const float*)d_in[28]; const float* fzd_b2 = (const float*)d_in[29];
    const float* fzd_g  = (const float*)d_in[30]; const float* fzd_b  = (const float*)d_in[31];

    float* out = (float*)d_out;
    float* ws = (float*)d_ws;
    size_t Rn = (size_t)LEN * DMODEL;
    float* Aq = ws;            // q, later h1 (post-LN1)
    float* Bv = ws + Rn;       // value, later ffn2 output
    float* Cc = ws + 2 * Rn;   // off(256) | attn logits(128)
    float* Dd = ws + 3 * Rn;   // msda out, later relu intermediates
    float* Ee = out;           // src2 scratch; final LN2 overwrites

    dim3 blk(256);
    int mgrid = (LEN + TS - 1) / TS;   // 140

    int n4 = LEN * DMODEL / 4;
    add_kernel<<<(n4 + 255) / 256, 256, 0, stream>>>(src, pos, Aq, n4);

    // value = src @ W_val^T + b_val
    gemm_mfma<false, false><<<dim3(384 / TS, mgrid), blk, 0, stream>>>(
        src, 384, W_val, b_val, nullptr, 0, Bv, 384, LEN, 384, 384);
    // off -> Cc[:, 0:256]
    gemm_mfma<false, false><<<dim3(256 / TS, mgrid), blk, 0, stream>>>(
        Aq, 384, W_off, b_off, nullptr, 0, Cc, 384, LEN, 256, 384);
    // attn logits -> Cc[:, 256:384]
    gemm_mfma<false, false><<<dim3(128 / TS, mgrid), blk, 0, stream>>>(
        Aq, 384, W_attn, b_attn, nullptr, 0, Cc + 256, 384, LEN, 128, 384);

    // MSDA sampling -> Dd
    msda_v2<<<(LEN + MTOK - 1) / MTOK, 384, 0, stream>>>(Bv, Cc, refpts, Dd);

    // src2 = msda @ W_out^T + b_out -> Ee
    gemm_mfma<false, false><<<dim3(384 / TS, mgrid), blk, 0, stream>>>(
        Dd, 384, W_out, b_out, nullptr, 0, Ee, 384, LEN, 384, 384);

    // h1 = LN1(src + src2) -> Aq
    ln_kernel<<<dim3(LEN, 2), 256, 0, stream>>>(src, Ee, g1xy, b1xy, g1zd, b1zd, Aq);

    // FFN first GEMMs (relu) -> Dd
    gemm_mfma<true, false><<<dim3(256 / TS, mgrid), blk, 0, stream>>>(
        Aq, 384, fxy_w1, fxy_b1, nullptr, 0, Dd, 384, LEN, 256, 256);
    gemm_mfma<true, false><<<dim3(128 / TS, mgrid), blk, 0, stream>>>(
        Aq + 256, 384, fzd_w1, fzd_b1, nullptr, 0, Dd + 256, 384, LEN, 128, 128);

    // FFN second GEMMs + residual(h1) -> Bv
    gemm_mfma<false, true><<<dim3(256 / TS, mgrid), blk, 0, stream>>>(
        Dd, 384, fxy_w2, fxy_b2, Aq, 384, Bv, 384, LEN, 256, 256);
    gemm_mfma<false, true><<<dim3(128 / TS, mgrid), blk, 0, stream>>>(
        Dd + 256, 384, fzd_w2, fzd_b2, Aq + 256, 384, Bv + 256, 384, LEN, 128, 128);

    // LN2 -> d_out
    ln_kernel<<<dim3(LEN, 2), 256, 0, stream>>>(Bv, nullptr, fxy_g, fxy_b, fzd_g, fzd_b, out);
}

// Round 3
// 402.796 us; speedup vs baseline: 2.5209x; 1.2503x over previous
//
#include <hip/hip_runtime.h>
#include <math.h>

#define LEN 17821
#define DMODEL 384
#define NHEAD 8
#define DHEAD 48
#define WSZ (384 * 384)

typedef float floatx4 __attribute__((ext_vector_type(4)));
typedef short shortx8 __attribute__((ext_vector_type(8)));
typedef unsigned short ushort;

__device__ inline ushort f2bf(float f) {
    unsigned int u = __float_as_uint(f);
    u += 0x7FFFu + ((u >> 16) & 1u);
    return (ushort)(u >> 16);
}
__device__ inline float bf2f(ushort s) {
    return __uint_as_float(((unsigned int)s) << 16);
}

// ---------------------------------------------------------------------------
// Weight prep: 5 jobs (blockIdx.y), each converts a [384,384] bf16 matrix.
//  0: W_val  1: [W_off;W_attn]  2: W_out  3: blockdiag(fxy_w1,fzd_w1)
//  4: blockdiag(fxy_w2,fzd_w2)
// ---------------------------------------------------------------------------
__global__ __launch_bounds__(256)
void prep_w(const float* __restrict__ Wval, const float* __restrict__ Woff,
            const float* __restrict__ Wattn, const float* __restrict__ Wout,
            const float* __restrict__ w1xy, const float* __restrict__ w1zd,
            const float* __restrict__ w2xy, const float* __restrict__ w2zd,
            ushort* __restrict__ wv, ushort* __restrict__ woa,
            ushort* __restrict__ wo, ushort* __restrict__ w1b,
            ushort* __restrict__ w2b) {
    int idx = blockIdx.x * 256 + threadIdx.x;
    if (idx >= WSZ) return;
    int n = idx / 384, k = idx - n * 384;
    int job = blockIdx.y;
    float v; ushort* dst;
    if (job == 0) { v = Wval[idx]; dst = wv; }
    else if (job == 1) {
        v = n < 256 ? Woff[n * 384 + k] : Wattn[(n - 256) * 384 + k];
        dst = woa;
    } else if (job == 2) { v = Wout[idx]; dst = wo; }
    else if (job == 3) {
        v = n < 256 ? (k < 256 ? w1xy[n * 256 + k] : 0.f)
                    : (k >= 256 ? w1zd[(n - 256) * 128 + (k - 256)] : 0.f);
        dst = w1b;
    } else {
        v = n < 256 ? (k < 256 ? w2xy[n * 256 + k] : 0.f)
                    : (k >= 256 ? w2zd[(n - 256) * 128 + (k - 256)] : 0.f);
        dst = w2b;
    }
    dst[idx] = f2bf(v);
}

__global__ __launch_bounds__(384)
void prep_b(const float* __restrict__ boff, const float* __restrict__ battn,
            const float* __restrict__ b1xy, const float* __restrict__ b1zd,
            const float* __restrict__ b2xy, const float* __restrict__ b2zd,
            float* __restrict__ boa, float* __restrict__ b1c,
            float* __restrict__ b2c) {
    int i = threadIdx.x;
    boa[i] = i < 256 ? boff[i] : battn[i - 256];
    b1c[i] = i < 256 ? b1xy[i] : b1zd[i - 256];
    b2c[i] = i < 256 ? b2xy[i] : b2zd[i - 256];
}

// ---------------------------------------------------------------------------
// src_bf = bf16(src); q_bf = bf16(src + pos). 8 elements/thread.
// ---------------------------------------------------------------------------
__global__ __launch_bounds__(256)
void cvt_add(const float* __restrict__ src, const float* __restrict__ pos,
             ushort* __restrict__ src_bf, ushort* __restrict__ q_bf, int n8) {
    int i = blockIdx.x * 256 + threadIdx.x;
    if (i >= n8) return;
    float4 s0 = ((const float4*)src)[i * 2], s1 = ((const float4*)src)[i * 2 + 1];
    float4 p0 = ((const float4*)pos)[i * 2], p1 = ((const float4*)pos)[i * 2 + 1];
    shortx8 sb, qb;
    sb[0] = f2bf(s0.x); sb[1] = f2bf(s0.y); sb[2] = f2bf(s0.z); sb[3] = f2bf(s0.w);
    sb[4] = f2bf(s1.x); sb[5] = f2bf(s1.y); sb[6] = f2bf(s1.z); sb[7] = f2bf(s1.w);
    qb[0] = f2bf(s0.x + p0.x); qb[1] = f2bf(s0.y + p0.y);
    qb[2] = f2bf(s0.z + p0.z); qb[3] = f2bf(s0.w + p0.w);
    qb[4] = f2bf(s1.x + p1.x); qb[5] = f2bf(s1.y + p1.y);
    qb[6] = f2bf(s1.z + p1.z); qb[7] = f2bf(s1.w + p1.w);
    ((shortx8*)src_bf)[i] = sb;
    ((shortx8*)q_bf)[i] = qb;
}

// ---------------------------------------------------------------------------
// bf16 MFMA GEMM, fixed M=LEN, N=K=384, lda=ldc=384.
// C = A @ W^T + bias (+relu) (+res). Output fp32 or bf16.
// 128x128 tile, BK=32, 4 waves 2x2, each 64x64 via 4x4 mfma_16x16x32_bf16.
// ---------------------------------------------------------------------------
#define TS 128
#define LSTRIDE 40

template<bool RELU, bool HAS_RES, bool OUT_BF>
__global__ __launch_bounds__(256)
void gemm_bf(const ushort* __restrict__ A, const ushort* __restrict__ W,
             const float* __restrict__ bias, const float* __restrict__ Res,
             float* __restrict__ Cf, ushort* __restrict__ Cb) {
    __shared__ ushort As[TS * LSTRIDE];
    __shared__ ushort Ws[TS * LSTRIDE];
    int tid = threadIdx.x;
    int lane = tid & 63, wave = tid >> 6;
    int wr = (wave >> 1) * 64, wc = (wave & 1) * 64;
    int l15 = lane & 15, quad = lane >> 4;
    int srow = tid >> 1, shalf = tid & 1;
    int by = blockIdx.y, bx = blockIdx.x;
    int garow = by * TS + srow;
    bool avalid = garow < LEN;
    const ushort* ap = A + (size_t)(avalid ? garow : 0) * 384 + shalf * 16;
    const ushort* wp = W + (size_t)(bx * TS + srow) * 384 + shalf * 16;
    ushort* as_dst = &As[srow * LSTRIDE + shalf * 16];
    ushort* ws_dst = &Ws[srow * LSTRIDE + shalf * 16];

    floatx4 acc[4][4];
    #pragma unroll
    for (int i = 0; i < 4; ++i)
        #pragma unroll
        for (int j = 0; j < 4; ++j)
            acc[i][j] = (floatx4){0.f, 0.f, 0.f, 0.f};

    for (int k0 = 0; k0 < 384; k0 += 32) {
        shortx8 a0 = *(const shortx8*)(ap + k0);
        shortx8 a1 = *(const shortx8*)(ap + k0 + 8);
        shortx8 w0 = *(const shortx8*)(wp + k0);
        shortx8 w1 = *(const shortx8*)(wp + k0 + 8);
        if (!avalid) { a0 = (shortx8)0; a1 = (shortx8)0; }
        __syncthreads();
        *(shortx8*)(as_dst + 0) = a0;
        *(shortx8*)(as_dst + 8) = a1;
        *(shortx8*)(ws_dst + 0) = w0;
        *(shortx8*)(ws_dst + 8) = w1;
        __syncthreads();
        shortx8 af[4], bfr[4];
        #pragma unroll
        for (int i = 0; i < 4; ++i)
            af[i] = *(shortx8*)&As[(wr + i * 16 + l15) * LSTRIDE + quad * 8];
        #pragma unroll
        for (int j = 0; j < 4; ++j)
            bfr[j] = *(shortx8*)&Ws[(wc + j * 16 + l15) * LSTRIDE + quad * 8];
        #pragma unroll
        for (int i = 0; i < 4; ++i)
            #pragma unroll
            for (int j = 0; j < 4; ++j)
                acc[i][j] = __builtin_amdgcn_mfma_f32_16x16x32_bf16(
                    af[i], bfr[j], acc[i][j], 0, 0, 0);
    }

    #pragma unroll
    for (int j = 0; j < 4; ++j) {
        int col = bx * TS + wc + j * 16 + l15;
        float bv = bias[col];
        #pragma unroll
        for (int i = 0; i < 4; ++i) {
            #pragma unroll
            for (int r = 0; r < 4; ++r) {
                int row = by * TS + wr + i * 16 + quad * 4 + r;
                if (row < LEN) {
                    float v = acc[i][j][r] + bv;
                    if (RELU) v = fmaxf(v, 0.f);
                    if (HAS_RES) v += Res[(size_t)row * 384 + col];
                    if (OUT_BF) Cb[(size_t)row * 384 + col] = f2bf(v);
                    else        Cf[(size_t)row * 384 + col] = v;
                }
            }
        }
    }
}

// ---------------------------------------------------------------------------
// MSDA v3: bf16 value gather. Block = 8 tokens x 48 threads (8 heads x 6
// 8-dim chunks). Phase 1: softmax + sample coords into LDS. Phase 2: gather.
// ---------------------------------------------------------------------------
#define MTOK 8
__global__ __launch_bounds__(384)
void msda_v3(const ushort* __restrict__ value,   // [LEN,384] bf16
             const float* __restrict__ offattn,  // [LEN,384] fp32
             const float* __restrict__ refpts,   // [LEN,4,2]
             ushort* __restrict__ out) {         // [LEN,384] bf16
    __shared__ int   sx0[MTOK * 128], sy0[MTOK * 128];
    __shared__ float sdx[MTOK * 128], sdy[MTOK * 128], saw[MTOK * 128];
    constexpr int Wi[4]  = {134, 67, 34, 17};
    constexpr int Hi[4]  = {100, 50, 25, 13};
    constexpr int STi[4] = {0, 13400, 16750, 17600};
    int t0 = blockIdx.x * MTOK;
    int tid = threadIdx.x;

    if (tid < MTOK * 8) {
        int ti = tid >> 3, h = tid & 7, t = t0 + ti;
        if (t < LEN) {
            const float* lg = offattn + (size_t)t * 384 + 256 + h * 16;
            float w[16], mx = -3.4e38f;
            #pragma unroll
            for (int s = 0; s < 16; ++s) { w[s] = lg[s]; mx = fmaxf(mx, w[s]); }
            float sum = 0.f;
            #pragma unroll
            for (int s = 0; s < 16; ++s) { w[s] = __expf(w[s] - mx); sum += w[s]; }
            float inv = 1.0f / sum;
            #pragma unroll
            for (int s = 0; s < 16; ++s) saw[ti * 128 + h * 16 + s] = w[s] * inv;
        }
    }
    for (int idx = tid; idx < MTOK * 128; idx += 384) {
        int ti = idx >> 7, rem = idx & 127, h = rem >> 4, p = rem & 15;
        int lvl = p >> 2, pp = p & 3;
        int t = t0 + ti;
        if (t < LEN) {
            float Wl = (float)Wi[lvl], Hl = (float)Hi[lvl];
            const float* op = offattn + (size_t)t * 384 + h * 32 + lvl * 8 + pp * 2;
            float ox = op[0], oy = op[1];
            float rx = refpts[(size_t)t * 8 + lvl * 2];
            float ry = refpts[(size_t)t * 8 + lvl * 2 + 1];
            float x = rx * Wl + ox - 0.5f;
            float y = ry * Hl + oy - 0.5f;
            float x0 = floorf(x), y0 = floorf(y);
            sx0[idx] = (int)x0; sy0[idx] = (int)y0;
            sdx[idx] = x - x0;  sdy[idx] = y - y0;
        }
    }
    __syncthreads();

    int ti = tid / 48;
    int r = tid - ti * 48;
    int h = r / 6;
    int c = r - h * 6;
    int t = t0 + ti;
    if (t >= LEN) return;
    const ushort* vb = value + h * DHEAD + c * 8;
    float a[8] = {};
    #pragma unroll
    for (int p = 0; p < 16; ++p) {
        const int lvl = p >> 2;
        const int Wl = Wi[lvl], Hl = Hi[lvl], st = STi[lvl];
        int base = ti * 128 + h * 16 + p;
        int x0 = sx0[base], y0 = sy0[base];
        float dx = sdx[base], dy = sdy[base], aw = saw[base];
        float cw0 = (1.f - dx) * (1.f - dy);
        float cw1 = dx * (1.f - dy);
        float cw2 = (1.f - dx) * dy;
        float cw3 = dx * dy;
        float cwv[4] = {cw0, cw1, cw2, cw3};
        #pragma unroll
        for (int c2 = 0; c2 < 4; ++c2) {
            int xi = x0 + (c2 & 1), yi = y0 + (c2 >> 1);
            bool valid = (xi >= 0) & (xi < Wl) & (yi >= 0) & (yi < Hl);
            int xc = min(max(xi, 0), Wl - 1);
            int yc = min(max(yi, 0), Hl - 1);
            float s = valid ? aw * cwv[c2] : 0.f;
            shortx8 g = *(const shortx8*)(vb + (size_t)(st + yc * Wl + xc) * 384);
            #pragma unroll
            for (int k = 0; k < 8; ++k) a[k] += s * bf2f(g[k]);
        }
    }
    shortx8 o;
    #pragma unroll
    for (int k = 0; k < 8; ++k) o[k] = f2bf(a[k]);
    *(shortx8*)(out + (size_t)t * 384 + h * DHEAD + c * 8) = o;
}

// ---------------------------------------------------------------------------
// Split LayerNorm; optional residual R; writes fp32 and optional bf16 copy.
// ---------------------------------------------------------------------------
__global__ __launch_bounds__(256)
void ln_kernel(const float* __restrict__ X, const float* __restrict__ R,
               const float* __restrict__ gxy, const float* __restrict__ bxy,
               const float* __restrict__ gzd, const float* __restrict__ bzd,
               float* __restrict__ outf, ushort* __restrict__ outb) {
    __shared__ float s1[256], s2[256];
    int t = blockIdx.x;
    int seg = blockIdx.y;
    int n = seg ? 128 : 256;
    int off = seg ? 256 : 0;
    const float* g = seg ? gzd : gxy;
    const float* b = seg ? bzd : bxy;
    int i = threadIdx.x;
    float x = 0.f;
    if (i < n) {
        x = X[(size_t)t * 384 + off + i];
        if (R) x += R[(size_t)t * 384 + off + i];
    }
    s1[i] = x; s2[i] = x * x;
    __syncthreads();
    for (int st = 128; st > 0; st >>= 1) {
        if (i < st) { s1[i] += s1[i + st]; s2[i] += s2[i + st]; }
        __syncthreads();
    }
    float m = s1[0] / n;
    float v = s2[0] / n - m * m;
    float iv = rsqrtf(v + 1e-5f);
    if (i < n) {
        float o = (x - m) * iv * g[i] + b[i];
        outf[(size_t)t * 384 + off + i] = o;
        if (outb) outb[(size_t)t * 384 + off + i] = f2bf(o);
    }
}

// ---------------------------------------------------------------------------
extern "C" void kernel_launch(void* const* d_in, const int* in_sizes, int n_in,
                              void* d_out, int out_size, void* d_ws, size_t ws_size,
                              hipStream_t stream) {
    const float* src    = (const float*)d_in[0];
    const float* pos    = (const float*)d_in[3];
    const float* refpts = (const float*)d_in[4];
    const float* W_off  = (const float*)d_in[8];
    const float* b_off  = (const float*)d_in[9];
    const float* W_attn = (const float*)d_in[10];
    const float* b_attn = (const float*)d_in[11];
    const float* W_val  = (const float*)d_in[12];
    const float* b_val  = (const float*)d_in[13];
    const float* W_out  = (const float*)d_in[14];
    const float* b_out  = (const float*)d_in[15];
    const float* g1xy = (const float*)d_in[16]; const float* b1xy = (const float*)d_in[17];
    const float* g1zd = (const float*)d_in[18]; const float* b1zd = (const float*)d_in[19];
    const float* fxy_w1 = (const float*)d_in[20]; const float* fxy_b1 = (const float*)d_in[21];
    const float* fxy_w2 = (const float*)d_in[22]; const float* fxy_b2 = (const float*)d_in[23];
    const float* fxy_g  = (const float*)d_in[24]; const float* fxy_b  = (const float*)d_in[25];
    const float* fzd_w1 = (const float*)d_in[26]; const float* fzd_b1 = (const float*)d_in[27];
    const float* fzd_w2 = (const float*)d_in[28]; const float* fzd_b2 = (const float*)d_in[29];
    const float* fzd_g  = (const float*)d_in[30]; const float* fzd_b  = (const float*)d_in[31];

    float* out = (float*)d_out;
    size_t Rn = (size_t)LEN * DMODEL;            // 6,843,264

    float* f0 = (float*)d_ws;                    // offattn fp32, later h1 fp32
    ushort* sb = (ushort*)(f0 + Rn);
    ushort* s0 = sb;                             // src_bf, later ffn-hidden bf
    ushort* s1 = sb + Rn;                        // q_bf
    ushort* s2 = sb + 2 * Rn;                    // value_bf
    ushort* s3 = sb + 3 * Rn;                    // msda_bf, later h1_bf
    ushort* wv  = sb + 4 * Rn;
    ushort* woa = wv + WSZ;
    ushort* wo  = woa + WSZ;
    ushort* w1b = wo + WSZ;
    ushort* w2b = w1b + WSZ;
    float* bpool = (float*)(w2b + WSZ);
    float* boa = bpool; float* b1c = bpool + 384; float* b2c = bpool + 768;

    dim3 blk(256);
    dim3 ggrid(3, (LEN + TS - 1) / TS);          // (3, 140)

    prep_w<<<dim3((WSZ + 255) / 256, 5), blk, 0, stream>>>(
        W_val, W_off, W_attn, W_out, fxy_w1, fzd_w1, fxy_w2, fzd_w2,
        wv, woa, wo, w1b, w2b);
    prep_b<<<1, 384, 0, stream>>>(b_off, b_attn, fxy_b1, fzd_b1, fxy_b2, fzd_b2,
                                  boa, b1c, b2c);

    int n8 = (int)(Rn / 8);
    cvt_add<<<(n8 + 255) / 256, blk, 0, stream>>>(src, pos, s0, s1, n8);

    // value (bf16 out)
    gemm_bf<false, false, true><<<ggrid, blk, 0, stream>>>(
        s0, wv, b_val, nullptr, nullptr, s2);
    // off|attn logits (fp32 out)
    gemm_bf<false, false, false><<<ggrid, blk, 0, stream>>>(
        s1, woa, boa, nullptr, f0, nullptr);

    // MSDA -> s3 (bf16)
    msda_v3<<<(LEN + MTOK - 1) / MTOK, 384, 0, stream>>>(s2, f0, refpts, s3);

    // src2 = msda @ W_out^T (fp32 -> d_out scratch)
    gemm_bf<false, false, false><<<ggrid, blk, 0, stream>>>(
        s3, wo, b_out, nullptr, out, nullptr);

    // h1 = LN1(src + src2): fp32 -> f0, bf16 -> s3
    ln_kernel<<<dim3(LEN, 2), blk, 0, stream>>>(
        src, out, g1xy, b1xy, g1zd, b1zd, f0, s3);

    // ffn hidden = relu(h1 @ W1blk^T + b1c) (bf16 -> s0)
    gemm_bf<true, false, true><<<ggrid, blk, 0, stream>>>(
        s3, w1b, b1c, nullptr, nullptr, s0);
    // ffn out = hidden @ W2blk^T + b2c + h1 (fp32 -> d_out)
    gemm_bf<false, true, false><<<ggrid, blk, 0, stream>>>(
        s0, w2b, b2c, f0, out, nullptr);

    // LN2 in-place on d_out
    ln_kernel<<<dim3(LEN, 2), blk, 0, stream>>>(
        out, nullptr, fxy_g, fxy_b, fzd_g, fzd_b, out, nullptr);
}

// Round 4
// 374.591 us; speedup vs baseline: 2.7107x; 1.0753x over previous
//
#include <hip/hip_runtime.h>
#include <math.h>

#define LEN 17821
#define DMODEL 384
#define NHEAD 8
#define DHEAD 48
#define WSZ (384 * 384)

typedef float floatx4 __attribute__((ext_vector_type(4)));
typedef short shortx8 __attribute__((ext_vector_type(8)));
typedef unsigned short ushort;

__device__ inline ushort f2bf(float f) {
    unsigned int u = __float_as_uint(f);
    u += 0x7FFFu + ((u >> 16) & 1u);
    return (ushort)(u >> 16);
}
__device__ inline float bf2f(ushort s) {
    return __uint_as_float(((unsigned int)s) << 16);
}

// ---------------------------------------------------------------------------
// Weight prep: 5 jobs, each emits a [384,384] bf16 matrix.
// ---------------------------------------------------------------------------
__global__ __launch_bounds__(256)
void prep_w(const float* __restrict__ Wval, const float* __restrict__ Woff,
            const float* __restrict__ Wattn, const float* __restrict__ Wout,
            const float* __restrict__ w1xy, const float* __restrict__ w1zd,
            const float* __restrict__ w2xy, const float* __restrict__ w2zd,
            ushort* __restrict__ wv, ushort* __restrict__ woa,
            ushort* __restrict__ wo, ushort* __restrict__ w1b,
            ushort* __restrict__ w2b) {
    int idx = blockIdx.x * 256 + threadIdx.x;
    if (idx >= WSZ) return;
    int n = idx / 384, k = idx - n * 384;
    int job = blockIdx.y;
    float v; ushort* dst;
    if (job == 0) { v = Wval[idx]; dst = wv; }
    else if (job == 1) {
        v = n < 256 ? Woff[n * 384 + k] : Wattn[(n - 256) * 384 + k];
        dst = woa;
    } else if (job == 2) { v = Wout[idx]; dst = wo; }
    else if (job == 3) {
        v = n < 256 ? (k < 256 ? w1xy[n * 256 + k] : 0.f)
                    : (k >= 256 ? w1zd[(n - 256) * 128 + (k - 256)] : 0.f);
        dst = w1b;
    } else {
        v = n < 256 ? (k < 256 ? w2xy[n * 256 + k] : 0.f)
                    : (k >= 256 ? w2zd[(n - 256) * 128 + (k - 256)] : 0.f);
        dst = w2b;
    }
    dst[idx] = f2bf(v);
}

// Bias / LN-param concat: boa, b1c, b2c, ln1g, ln1b, ln2g, ln2b (384 each).
__global__ __launch_bounds__(384)
void prep_b(const float* __restrict__ boff, const float* __restrict__ battn,
            const float* __restrict__ b1xy, const float* __restrict__ b1zd,
            const float* __restrict__ b2xy, const float* __restrict__ b2zd,
            const float* __restrict__ g1xy, const float* __restrict__ be1xy,
            const float* __restrict__ g1zd, const float* __restrict__ be1zd,
            const float* __restrict__ g2xy, const float* __restrict__ be2xy,
            const float* __restrict__ g2zd, const float* __restrict__ be2zd,
            float* __restrict__ boa, float* __restrict__ b1c,
            float* __restrict__ b2c, float* __restrict__ l1g,
            float* __restrict__ l1b, float* __restrict__ l2g,
            float* __restrict__ l2b) {
    int i = threadIdx.x;
    bool lo = i < 256; int j = lo ? i : i - 256;
    boa[i] = lo ? boff[i] : battn[j];
    b1c[i] = lo ? b1xy[i] : b1zd[j];
    b2c[i] = lo ? b2xy[i] : b2zd[j];
    l1g[i] = lo ? g1xy[i] : g1zd[j];
    l1b[i] = lo ? be1xy[i] : be1zd[j];
    l2g[i] = lo ? g2xy[i] : g2zd[j];
    l2b[i] = lo ? be2xy[i] : be2zd[j];
}

// ---------------------------------------------------------------------------
// src_bf = bf16(src); q_bf = bf16(src + pos).
// ---------------------------------------------------------------------------
__global__ __launch_bounds__(256)
void cvt_add(const float* __restrict__ src, const float* __restrict__ pos,
             ushort* __restrict__ src_bf, ushort* __restrict__ q_bf, int n8) {
    int i = blockIdx.x * 256 + threadIdx.x;
    if (i >= n8) return;
    float4 s0 = ((const float4*)src)[i * 2], s1 = ((const float4*)src)[i * 2 + 1];
    float4 p0 = ((const float4*)pos)[i * 2], p1 = ((const float4*)pos)[i * 2 + 1];
    shortx8 sb, qb;
    sb[0] = f2bf(s0.x); sb[1] = f2bf(s0.y); sb[2] = f2bf(s0.z); sb[3] = f2bf(s0.w);
    sb[4] = f2bf(s1.x); sb[5] = f2bf(s1.y); sb[6] = f2bf(s1.z); sb[7] = f2bf(s1.w);
    qb[0] = f2bf(s0.x + p0.x); qb[1] = f2bf(s0.y + p0.y);
    qb[2] = f2bf(s0.z + p0.z); qb[3] = f2bf(s0.w + p0.w);
    qb[4] = f2bf(s1.x + p1.x); qb[5] = f2bf(s1.y + p1.y);
    qb[6] = f2bf(s1.z + p1.z); qb[7] = f2bf(s1.w + p1.w);
    ((shortx8*)src_bf)[i] = sb;
    ((shortx8*)q_bf)[i] = qb;
}

// ---------------------------------------------------------------------------
// Merged value + offattn GEMM. grid (6,140): bx<3 -> value (bf16 out),
// bx>=3 -> offattn (fp32 out). 128x128 tile, BK=32, mfma 16x16x32 bf16.
// ---------------------------------------------------------------------------
#define TSV 128
#define LSTRIDE 40

__global__ __launch_bounds__(256)
void vq_gemm(const ushort* __restrict__ sbq, const ushort* __restrict__ qbq,
             const ushort* __restrict__ wv, const ushort* __restrict__ woa,
             const float* __restrict__ bval, const float* __restrict__ boa,
             ushort* __restrict__ vout, float* __restrict__ oaout) {
    __shared__ ushort As[TSV * LSTRIDE];
    __shared__ ushort Ws[TSV * LSTRIDE];
    bool job = blockIdx.x >= 3;
    int bx = job ? blockIdx.x - 3 : blockIdx.x;
    const ushort* A = job ? qbq : sbq;
    const ushort* W = job ? woa : wv;
    const float* bias = job ? boa : bval;
    int tid = threadIdx.x;
    int lane = tid & 63, wave = tid >> 6;
    int wr = (wave >> 1) * 64, wc = (wave & 1) * 64;
    int l15 = lane & 15, quad = lane >> 4;
    int srow = tid >> 1, shalf = tid & 1;
    int by = blockIdx.y;
    int garow = by * TSV + srow;
    bool avalid = garow < LEN;
    const ushort* ap = A + (size_t)(avalid ? garow : 0) * 384 + shalf * 16;
    const ushort* wp = W + (size_t)(bx * TSV + srow) * 384 + shalf * 16;
    ushort* as_dst = &As[srow * LSTRIDE + shalf * 16];
    ushort* ws_dst = &Ws[srow * LSTRIDE + shalf * 16];

    floatx4 acc[4][4];
    #pragma unroll
    for (int i = 0; i < 4; ++i)
        #pragma unroll
        for (int j = 0; j < 4; ++j)
            acc[i][j] = (floatx4){0.f, 0.f, 0.f, 0.f};

    for (int k0 = 0; k0 < 384; k0 += 32) {
        shortx8 a0 = *(const shortx8*)(ap + k0);
        shortx8 a1 = *(const shortx8*)(ap + k0 + 8);
        shortx8 w0 = *(const shortx8*)(wp + k0);
        shortx8 w1 = *(const shortx8*)(wp + k0 + 8);
        __syncthreads();
        *(shortx8*)(as_dst + 0) = a0;
        *(shortx8*)(as_dst + 8) = a1;
        *(shortx8*)(ws_dst + 0) = w0;
        *(shortx8*)(ws_dst + 8) = w1;
        __syncthreads();
        shortx8 af[4], bfr[4];
        #pragma unroll
        for (int i = 0; i < 4; ++i)
            af[i] = *(shortx8*)&As[(wr + i * 16 + l15) * LSTRIDE + quad * 8];
        #pragma unroll
        for (int j = 0; j < 4; ++j)
            bfr[j] = *(shortx8*)&Ws[(wc + j * 16 + l15) * LSTRIDE + quad * 8];
        #pragma unroll
        for (int i = 0; i < 4; ++i)
            #pragma unroll
            for (int j = 0; j < 4; ++j)
                acc[i][j] = __builtin_amdgcn_mfma_f32_16x16x32_bf16(
                    af[i], bfr[j], acc[i][j], 0, 0, 0);
    }

    #pragma unroll
    for (int j = 0; j < 4; ++j) {
        int col = bx * TSV + wc + j * 16 + l15;
        float bv = bias[col];
        #pragma unroll
        for (int i = 0; i < 4; ++i) {
            #pragma unroll
            for (int r = 0; r < 4; ++r) {
                int row = by * TSV + wr + i * 16 + quad * 4 + r;
                if (row < LEN) {
                    float v = acc[i][j][r] + bv;
                    if (job) oaout[(size_t)row * 384 + col] = v;
                    else     vout[(size_t)row * 384 + col] = f2bf(v);
                }
            }
        }
    }
}

// ---------------------------------------------------------------------------
// MSDA v4: phase1 precomputes per-corner (weight, row byte-offset) pairs in
// padded LDS (pitch 65 -> conflict-free ds_read_b64 in phase 2). XCD swizzle
// groups contiguous token chunks per XCD for L2 locality.
// ---------------------------------------------------------------------------
#define MTOK 8
__global__ __launch_bounds__(384)
void msda_v4(const ushort* __restrict__ value,   // [LEN,384] bf16
             const float* __restrict__ offattn,  // [LEN,384] fp32
             const float* __restrict__ refpts,   // [LEN,4,2]
             ushort* __restrict__ out) {         // [LEN,384] bf16
    __shared__ float saw[MTOK * 128];
    __shared__ int   sbuf[MTOK * 8 * 65 * 2];
    constexpr int Wi[4]  = {134, 67, 34, 17};
    constexpr int Hi[4]  = {100, 50, 25, 13};
    constexpr int STi[4] = {0, 13400, 16750, 17600};
    int b = blockIdx.x;                  // grid = 2232 = 8*279
    int nc = (b & 7) * 279 + (b >> 3);   // bijection; contiguous chunks per XCD
    int t0 = nc * MTOK;
    if (t0 >= LEN) return;
    int tid = threadIdx.x;

    if (tid < MTOK * 8) {
        int ti = tid >> 3, h = tid & 7, t = t0 + ti;
        if (t < LEN) {
            const float* lg = offattn + (size_t)t * 384 + 256 + h * 16;
            float w[16], mx = -3.4e38f;
            #pragma unroll
            for (int s = 0; s < 16; ++s) { w[s] = lg[s]; mx = fmaxf(mx, w[s]); }
            float sum = 0.f;
            #pragma unroll
            for (int s = 0; s < 16; ++s) { w[s] = __expf(w[s] - mx); sum += w[s]; }
            float inv = 1.0f / sum;
            #pragma unroll
            for (int s = 0; s < 16; ++s) saw[ti * 128 + h * 16 + s] = w[s] * inv;
        }
    }
    __syncthreads();

    for (int idx = tid; idx < MTOK * 128; idx += 384) {
        int ti = idx >> 7, rem = idx & 127, h = rem >> 4, p = rem & 15;
        int lvl = p >> 2, pp = p & 3;
        int t = t0 + ti;
        if (t < LEN) {
            int Wl = Wi[lvl], Hl = Hi[lvl];
            const float* op = offattn + (size_t)t * 384 + h * 32 + lvl * 8 + pp * 2;
            float ox = op[0], oy = op[1];
            float rx = refpts[(size_t)t * 8 + lvl * 2];
            float ry = refpts[(size_t)t * 8 + lvl * 2 + 1];
            float x = rx * (float)Wl + ox - 0.5f;
            float y = ry * (float)Hl + oy - 0.5f;
            float x0f = floorf(x), y0f = floorf(y);
            float dx = x - x0f, dy = y - y0f;
            int x0 = (int)x0f, y0 = (int)y0f;
            float aw = saw[ti * 128 + h * 16 + p];
            float cw[4] = {(1.f - dx) * (1.f - dy), dx * (1.f - dy),
                           (1.f - dx) * dy, dx * dy};
            int base = ((ti * 8 + h) * 65 + p * 4) * 2;
            #pragma unroll
            for (int c2 = 0; c2 < 4; ++c2) {
                int xi = x0 + (c2 & 1), yi = y0 + (c2 >> 1);
                bool valid = (xi >= 0) & (xi < Wl) & (yi >= 0) & (yi < Hl);
                int xc = min(max(xi, 0), Wl - 1);
                int yc = min(max(yi, 0), Hl - 1);
                float s = valid ? aw * cw[c2] : 0.f;
                int off = (STi[lvl] + yc * Wl + xc) * 768;  // row byte offset
                sbuf[base + c2 * 2]     = __float_as_int(s);
                sbuf[base + c2 * 2 + 1] = off;
            }
        }
    }
    __syncthreads();

    int ti = tid / 48;
    int r = tid - ti * 48;
    int h = r / 6;
    int c = r - h * 6;
    int t = t0 + ti;
    if (t >= LEN) return;
    const char* vb = (const char*)value + (h * DHEAD + c * 8) * 2;
    float a[8] = {};
    int gb = (ti * 8 + h) * 65 * 2;
    #pragma unroll 8
    for (int pc = 0; pc < 64; ++pc) {
        int2 pr = *(int2*)&sbuf[gb + pc * 2];
        float s = __int_as_float(pr.x);
        shortx8 g = *(const shortx8*)(vb + pr.y);
        #pragma unroll
        for (int e = 0; e < 8; ++e) a[e] += s * bf2f(g[e]);
    }
    shortx8 o;
    #pragma unroll
    for (int e = 0; e < 8; ++e) o[e] = f2bf(a[e]);
    *(shortx8*)(out + (size_t)t * 384 + h * DHEAD + c * 8) = o;
}

// ---------------------------------------------------------------------------
// MEGA: out-proj + LN1 + FFN1(relu) + FFN2 + LN2, one block per 32 rows,
// full N=384 per block. 4 waves, wave w covers cols [w*96, w*96+96).
// h1/hidden/x live in LDS (Cbuf); h1 fp32 round-trips via global (residual).
// ---------------------------------------------------------------------------
#define MT 32
#define CST 392    // Cbuf ushort stride: 392*2=784=16*49 (aligned, 2-way banks)
#define WST 40

__global__ __launch_bounds__(256)
void mega_kernel(const ushort* __restrict__ Amsda, const float* __restrict__ src,
                 const ushort* __restrict__ Wo, const ushort* __restrict__ W1,
                 const ushort* __restrict__ W2,
                 const float* __restrict__ bo, const float* __restrict__ b1c,
                 const float* __restrict__ b2c,
                 const float* __restrict__ l1g, const float* __restrict__ l1b,
                 const float* __restrict__ l2g, const float* __restrict__ l2b,
                 float* __restrict__ h1f, float* __restrict__ outp) {
    __shared__ __align__(16) ushort Wbuf[384 * WST];   // 30720 B
    __shared__ __align__(16) ushort Cbuf[MT * CST];    // 25088 B
    ushort* Abuf = Cbuf;                               // stage-1 A staging alias
    floatx4* pst4 = (floatx4*)Wbuf;                    // stats alias (Wbuf dead)
    floatx4* lnf  = (floatx4*)((char*)Wbuf + 4096);

    int tid = threadIdx.x;
    int lane = tid & 63, wave = tid >> 6;
    int wcol = wave * 96;
    int l15 = lane & 15, quad = lane >> 4;
    int by0 = blockIdx.x * MT;

    floatx4 acc[2][6];

    // ---------------- stage 1: src2 = msda @ Wo^T ----------------
    #pragma unroll
    for (int i = 0; i < 2; ++i)
        #pragma unroll
        for (int j = 0; j < 6; ++j) acc[i][j] = (floatx4){0.f, 0.f, 0.f, 0.f};

    for (int k0 = 0; k0 < 384; k0 += 32) {
        shortx8 areg;
        if (tid < 128) {
            int arow = tid >> 2, akc = tid & 3;
            int gr = min(by0 + arow, LEN - 1);
            areg = *(const shortx8*)(Amsda + (size_t)gr * 384 + k0 + akc * 8);
        }
        shortx8 wreg[6];
        #pragma unroll
        for (int cix = 0; cix < 6; ++cix) {
            int idx = cix * 256 + tid;
            wreg[cix] = *(const shortx8*)(Wo + (size_t)(idx >> 2) * 384 + k0 + (idx & 3) * 8);
        }
        __syncthreads();
        if (tid < 128) *(shortx8*)(Abuf + (tid >> 2) * WST + (tid & 3) * 8) = areg;
        #pragma unroll
        for (int cix = 0; cix < 6; ++cix) {
            int idx = cix * 256 + tid;
            *(shortx8*)(Wbuf + (idx >> 2) * WST + (idx & 3) * 8) = wreg[cix];
        }
        __syncthreads();
        shortx8 af[2];
        af[0] = *(shortx8*)(Abuf + (l15) * WST + quad * 8);
        af[1] = *(shortx8*)(Abuf + (16 + l15) * WST + quad * 8);
        #pragma unroll
        for (int j = 0; j < 6; ++j) {
            shortx8 bfr = *(shortx8*)(Wbuf + (wcol + j * 16 + l15) * WST + quad * 8);
            acc[0][j] = __builtin_amdgcn_mfma_f32_16x16x32_bf16(af[0], bfr, acc[0][j], 0, 0, 0);
            acc[1][j] = __builtin_amdgcn_mfma_f32_16x16x32_bf16(af[1], bfr, acc[1][j], 0, 0, 0);
        }
    }
    __syncthreads();

    // epilogue 1: x = src2 + b_out + src -> Cbuf (bf16)
    #pragma unroll
    for (int j = 0; j < 6; ++j) {
        int col = wcol + j * 16 + l15;
        float bv = bo[col];
        #pragma unroll
        for (int i = 0; i < 2; ++i)
            #pragma unroll
            for (int rr = 0; rr < 4; ++rr) {
                int row = i * 16 + quad * 4 + rr;
                int gr = min(by0 + row, LEN - 1);
                float x = acc[i][j][rr] + bv + src[(size_t)gr * 384 + col];
                Cbuf[row * CST + col] = f2bf(x);
            }
    }
    __syncthreads();

    // ---- LN helper phases (stats + finalize + normalize), LN1 ----
    {
        int row = tid >> 3, part = tid & 7;
        float sx = 0.f, qx = 0.f, sz = 0.f, qz = 0.f;
        #pragma unroll
        for (int m = 0; m < 6; ++m) {
            int c0 = part * 48 + m * 8;
            shortx8 v = *(shortx8*)(Cbuf + row * CST + c0);
            float cs = 0.f, cq = 0.f;
            #pragma unroll
            for (int e = 0; e < 8; ++e) { float x = bf2f(v[e]); cs += x; cq += x * x; }
            if (c0 < 256) { sx += cs; qx += cq; } else { sz += cs; qz += cq; }
        }
        pst4[row * 8 + part] = (floatx4){sx, qx, sz, qz};
    }
    __syncthreads();
    if (tid < MT) {
        floatx4 s = (floatx4){0.f, 0.f, 0.f, 0.f};
        #pragma unroll
        for (int p = 0; p < 8; ++p) s += pst4[tid * 8 + p];
        float mx = s[0] / 256.f, vx = s[1] / 256.f - mx * mx;
        float mz = s[2] / 128.f, vz = s[3] / 128.f - mz * mz;
        lnf[tid] = (floatx4){mx, rsqrtf(vx + 1e-5f), mz, rsqrtf(vz + 1e-5f)};
    }
    __syncthreads();
    {
        int row = tid >> 3, part = tid & 7;
        int gr = by0 + row;
        floatx4 L = lnf[row];
        #pragma unroll
        for (int m = 0; m < 6; ++m) {
            int c0 = part * 48 + m * 8;
            bool isxy = c0 < 256;
            float mean = isxy ? L[0] : L[2];
            float inv  = isxy ? L[1] : L[3];
            shortx8 v = *(shortx8*)(Cbuf + row * CST + c0);
            float4 g0 = *(const float4*)(l1g + c0), g1 = *(const float4*)(l1g + c0 + 4);
            float4 e0 = *(const float4*)(l1b + c0), e1 = *(const float4*)(l1b + c0 + 4);
            float gg[8] = {g0.x, g0.y, g0.z, g0.w, g1.x, g1.y, g1.z, g1.w};
            float ee[8] = {e0.x, e0.y, e0.z, e0.w, e1.x, e1.y, e1.z, e1.w};
            float h[8];
            shortx8 hb;
            #pragma unroll
            for (int e = 0; e < 8; ++e) {
                h[e] = (bf2f(v[e]) - mean) * inv * gg[e] + ee[e];
                hb[e] = f2bf(h[e]);
            }
            *(shortx8*)(Cbuf + row * CST + c0) = hb;
            if (gr < LEN) {
                *(float4*)(h1f + (size_t)gr * 384 + c0)     = make_float4(h[0], h[1], h[2], h[3]);
                *(float4*)(h1f + (size_t)gr * 384 + c0 + 4) = make_float4(h[4], h[5], h[6], h[7]);
            }
        }
    }
    __syncthreads();

    // ---------------- stage 2: hidden = relu(h1 @ W1^T + b1) ----------------
    #pragma unroll
    for (int i = 0; i < 2; ++i)
        #pragma unroll
        for (int j = 0; j < 6; ++j) acc[i][j] = (floatx4){0.f, 0.f, 0.f, 0.f};
    for (int k0 = 0; k0 < 384; k0 += 32) {
        shortx8 wreg[6];
        #pragma unroll
        for (int cix = 0; cix < 6; ++cix) {
            int idx = cix * 256 + tid;
            wreg[cix] = *(const shortx8*)(W1 + (size_t)(idx >> 2) * 384 + k0 + (idx & 3) * 8);
        }
        __syncthreads();
        #pragma unroll
        for (int cix = 0; cix < 6; ++cix) {
            int idx = cix * 256 + tid;
            *(shortx8*)(Wbuf + (idx >> 2) * WST + (idx & 3) * 8) = wreg[cix];
        }
        __syncthreads();
        shortx8 af[2];
        af[0] = *(shortx8*)(Cbuf + (l15) * CST + k0 + quad * 8);
        af[1] = *(shortx8*)(Cbuf + (16 + l15) * CST + k0 + quad * 8);
        #pragma unroll
        for (int j = 0; j < 6; ++j) {
            shortx8 bfr = *(shortx8*)(Wbuf + (wcol + j * 16 + l15) * WST + quad * 8);
            acc[0][j] = __builtin_amdgcn_mfma_f32_16x16x32_bf16(af[0], bfr, acc[0][j], 0, 0, 0);
            acc[1][j] = __builtin_amdgcn_mfma_f32_16x16x32_bf16(af[1], bfr, acc[1][j], 0, 0, 0);
        }
    }
    __syncthreads();
    #pragma unroll
    for (int j = 0; j < 6; ++j) {
        int col = wcol + j * 16 + l15;
        float bv = b1c[col];
        #pragma unroll
        for (int i = 0; i < 2; ++i)
            #pragma unroll
            for (int rr = 0; rr < 4; ++rr) {
                int row = i * 16 + quad * 4 + rr;
                Cbuf[row * CST + col] = f2bf(fmaxf(acc[i][j][rr] + bv, 0.f));
            }
    }
    __syncthreads();

    // ---------------- stage 3: x2 = hidden @ W2^T + b2 + h1 ----------------
    #pragma unroll
    for (int i = 0; i < 2; ++i)
        #pragma unroll
        for (int j = 0; j < 6; ++j) acc[i][j] = (floatx4){0.f, 0.f, 0.f, 0.f};
    for (int k0 = 0; k0 < 384; k0 += 32) {
        shortx8 wreg[6];
        #pragma unroll
        for (int cix = 0; cix < 6; ++cix) {
            int idx = cix * 256 + tid;
            wreg[cix] = *(const shortx8*)(W2 + (size_t)(idx >> 2) * 384 + k0 + (idx & 3) * 8);
        }
        __syncthreads();
        #pragma unroll
        for (int cix = 0; cix < 6; ++cix) {
            int idx = cix * 256 + tid;
            *(shortx8*)(Wbuf + (idx >> 2) * WST + (idx & 3) * 8) = wreg[cix];
        }
        __syncthreads();
        shortx8 af[2];
        af[0] = *(shortx8*)(Cbuf + (l15) * CST + k0 + quad * 8);
        af[1] = *(shortx8*)(Cbuf + (16 + l15) * CST + k0 + quad * 8);
        #pragma unroll
        for (int j = 0; j < 6; ++j) {
            shortx8 bfr = *(shortx8*)(Wbuf + (wcol + j * 16 + l15) * WST + quad * 8);
            acc[0][j] = __builtin_amdgcn_mfma_f32_16x16x32_bf16(af[0], bfr, acc[0][j], 0, 0, 0);
            acc[1][j] = __builtin_amdgcn_mfma_f32_16x16x32_bf16(af[1], bfr, acc[1][j], 0, 0, 0);
        }
    }
    __syncthreads();
    #pragma unroll
    for (int j = 0; j < 6; ++j) {
        int col = wcol + j * 16 + l15;
        float bv = b2c[col];
        #pragma unroll
        for (int i = 0; i < 2; ++i)
            #pragma unroll
            for (int rr = 0; rr < 4; ++rr) {
                int row = i * 16 + quad * 4 + rr;
                int gr = min(by0 + row, LEN - 1);
                float x = acc[i][j][rr] + bv + h1f[(size_t)gr * 384 + col];
                Cbuf[row * CST + col] = f2bf(x);
            }
    }
    __syncthreads();

    // LN2 stats + finalize + normalize -> d_out (fp32)
    {
        int row = tid >> 3, part = tid & 7;
        float sx = 0.f, qx = 0.f, sz = 0.f, qz = 0.f;
        #pragma unroll
        for (int m = 0; m < 6; ++m) {
            int c0 = part * 48 + m * 8;
            shortx8 v = *(shortx8*)(Cbuf + row * CST + c0);
            float cs = 0.f, cq = 0.f;
            #pragma unroll
            for (int e = 0; e < 8; ++e) { float x = bf2f(v[e]); cs += x; cq += x * x; }
            if (c0 < 256) { sx += cs; qx += cq; } else { sz += cs; qz += cq; }
        }
        pst4[row * 8 + part] = (floatx4){sx, qx, sz, qz};
    }
    __syncthreads();
    if (tid < MT) {
        floatx4 s = (floatx4){0.f, 0.f, 0.f, 0.f};
        #pragma unroll
        for (int p = 0; p < 8; ++p) s += pst4[tid * 8 + p];
        float mx = s[0] / 256.f, vx = s[1] / 256.f - mx * mx;
        float mz = s[2] / 128.f, vz = s[3] / 128.f - mz * mz;
        lnf[tid] = (floatx4){mx, rsqrtf(vx + 1e-5f), mz, rsqrtf(vz + 1e-5f)};
    }
    __syncthreads();
    {
        int row = tid >> 3, part = tid & 7;
        int gr = by0 + row;
        if (gr < LEN) {
            floatx4 L = lnf[row];
            #pragma unroll
            for (int m = 0; m < 6; ++m) {
                int c0 = part * 48 + m * 8;
                bool isxy = c0 < 256;
                float mean = isxy ? L[0] : L[2];
                float inv  = isxy ? L[1] : L[3];
                shortx8 v = *(shortx8*)(Cbuf + row * CST + c0);
                float4 g0 = *(const float4*)(l2g + c0), g1 = *(const float4*)(l2g + c0 + 4);
                float4 e0 = *(const float4*)(l2b + c0), e1 = *(const float4*)(l2b + c0 + 4);
                float gg[8] = {g0.x, g0.y, g0.z, g0.w, g1.x, g1.y, g1.z, g1.w};
                float ee[8] = {e0.x, e0.y, e0.z, e0.w, e1.x, e1.y, e1.z, e1.w};
                float h[8];
                #pragma unroll
                for (int e = 0; e < 8; ++e)
                    h[e] = (bf2f(v[e]) - mean) * inv * gg[e] + ee[e];
                *(float4*)(outp + (size_t)gr * 384 + c0)     = make_float4(h[0], h[1], h[2], h[3]);
                *(float4*)(outp + (size_t)gr * 384 + c0 + 4) = make_float4(h[4], h[5], h[6], h[7]);
            }
        }
    }
}

// ---------------------------------------------------------------------------
extern "C" void kernel_launch(void* const* d_in, const int* in_sizes, int n_in,
                              void* d_out, int out_size, void* d_ws, size_t ws_size,
                              hipStream_t stream) {
    const float* src    = (const float*)d_in[0];
    const float* pos    = (const float*)d_in[3];
    const float* refpts = (const float*)d_in[4];
    const float* W_off  = (const float*)d_in[8];
    const float* b_off  = (const float*)d_in[9];
    const float* W_attn = (const float*)d_in[10];
    const float* b_attn = (const float*)d_in[11];
    const float* W_val  = (const float*)d_in[12];
    const float* b_val  = (const float*)d_in[13];
    const float* W_out  = (const float*)d_in[14];
    const float* b_out  = (const float*)d_in[15];
    const float* g1xy = (const float*)d_in[16]; const float* b1xy = (const float*)d_in[17];
    const float* g1zd = (const float*)d_in[18]; const float* b1zd = (const float*)d_in[19];
    const float* fxy_w1 = (const float*)d_in[20]; const float* fxy_b1 = (const float*)d_in[21];
    const float* fxy_w2 = (const float*)d_in[22]; const float* fxy_b2 = (const float*)d_in[23];
    const float* fxy_g  = (const float*)d_in[24]; const float* fxy_b  = (const float*)d_in[25];
    const float* fzd_w1 = (const float*)d_in[26]; const float* fzd_b1 = (const float*)d_in[27];
    const float* fzd_w2 = (const float*)d_in[28]; const float* fzd_b2 = (const float*)d_in[29];
    const float* fzd_g  = (const float*)d_in[30]; const float* fzd_b  = (const float*)d_in[31];

    float* out = (float*)d_out;
    size_t Rn = (size_t)LEN * DMODEL;

    float* f0 = (float*)d_ws;                 // offattn fp32, later h1 fp32
    ushort* sb = (ushort*)(f0 + Rn);
    ushort* s0 = sb;                          // src_bf
    ushort* s1 = sb + Rn;                     // q_bf
    ushort* s2 = sb + 2 * Rn;                 // value_bf
    ushort* s3 = sb + 3 * Rn;                 // msda_bf
    ushort* wv  = sb + 4 * Rn;
    ushort* woa = wv + WSZ;
    ushort* wo  = woa + WSZ;
    ushort* w1b = wo + WSZ;
    ushort* w2b = w1b + WSZ;
    float* bp = (float*)(w2b + WSZ);
    float* boa = bp;        float* b1c = bp + 384;  float* b2c = bp + 768;
    float* l1g = bp + 1152; float* l1b = bp + 1536;
    float* l2g = bp + 1920; float* l2b = bp + 2304;

    dim3 blk(256);

    prep_w<<<dim3((WSZ + 255) / 256, 5), blk, 0, stream>>>(
        W_val, W_off, W_attn, W_out, fxy_w1, fzd_w1, fxy_w2, fzd_w2,
        wv, woa, wo, w1b, w2b);
    prep_b<<<1, 384, 0, stream>>>(b_off, b_attn, fxy_b1, fzd_b1, fxy_b2, fzd_b2,
                                  g1xy, b1xy, g1zd, b1zd, fxy_g, fxy_b, fzd_g, fzd_b,
                                  boa, b1c, b2c, l1g, l1b, l2g, l2b);

    int n8 = (int)(Rn / 8);
    cvt_add<<<(n8 + 255) / 256, blk, 0, stream>>>(src, pos, s0, s1, n8);

    vq_gemm<<<dim3(6, (LEN + TSV - 1) / TSV), blk, 0, stream>>>(
        s0, s1, wv, woa, b_val, boa, s2, f0);

    msda_v4<<<8 * 279, 384, 0, stream>>>(s2, f0, refpts, s3);

    mega_kernel<<<(LEN + MT - 1) / MT, blk, 0, stream>>>(
        s3, src, wo, w1b, w2b, b_out, b1c, b2c,
        l1g, l1b, l2g, l2b, f0, out);
}